// Round 15
// baseline (352.259 us; speedup 1.0000x reference)
//
#include <hip/hip_runtime.h>
#include <hip/hip_bf16.h>

#define S_ 4
#define B_ 256
#define L_ 256
#define D_ 512
#define NQ_ 4
#define H_ 2048
#define G_ 3072

typedef __attribute__((ext_vector_type(4))) float f32x4;
typedef __attribute__((ext_vector_type(8))) short s16x8;

__device__ __forceinline__ unsigned short f2bf(float x) {
    __hip_bfloat16 hb = __float2bfloat16(x);
    return reinterpret_cast<unsigned short&>(hb);
}

__device__ __forceinline__ f32x4 ntload4(const float* p) {
    return __builtin_nontemporal_load(reinterpret_cast<const f32x4*>(p));
}

__device__ __forceinline__ float ntload1(const float* p) {
    return __builtin_nontemporal_load(p);
}

// async global->LDS, 16B per lane, LDS dest = wave-uniform base + lane*16
__device__ __forceinline__ void gll16(const void* g, void* l) {
    __builtin_amdgcn_global_load_lds(
        (const __attribute__((address_space(1))) unsigned int*)g,
        (__attribute__((address_space(3))) unsigned int*)l, 16, 0, 0);
}

// block-wide sum for 256-thread blocks; red is __shared__ float[8]
__device__ __forceinline__ float block_sum256(float v, float* red) {
    #pragma unroll
    for (int off = 32; off > 0; off >>= 1) v += __shfl_down(v, off, 64);
    int tid = threadIdx.x;
    int lane = tid & 63, wid = tid >> 6;
    if (lane == 0) red[wid] = v;
    __syncthreads();
    float r = (tid < 4) ? red[tid] : 0.f;
    #pragma unroll
    for (int off = 4; off > 0; off >>= 1) r += __shfl_down(r, off, 64);
    if (tid == 0) red[0] = r;
    __syncthreads();
    float out = red[0];
    __syncthreads();
    return out;
}

// ---------------- kernel 1: masked mean pool over L ----------------
__global__ __launch_bounds__(256) void pool_kernel(
    const float* __restrict__ seq_tokens,
    const unsigned char* __restrict__ masks_raw,
    float* __restrict__ pooled)                // (S,B,D)
{
    const int sb = blockIdx.x;
    const int tid = threadIdx.x;
    __shared__ float sval[L_];
    __shared__ float scount[4];
    __shared__ f32x4 spart[256];
    __shared__ int is_bool_flag;

    if (tid == 0) is_bool_flag = 0;
    __syncthreads();
    {
        unsigned int w = reinterpret_cast<const unsigned int*>(masks_raw)[tid];
        if (w & 0xFFFFFF00u) is_bool_flag = 1;   // benign race, same value
    }
    __syncthreads();
    const bool is_bool = (is_bool_flag != 0);

    int mval;
    if (is_bool) mval = masks_raw[(size_t)sb * L_ + tid];
    else         mval = reinterpret_cast<const int*>(masks_raw)[(size_t)sb * L_ + tid];
    float valid = mval ? 0.f : 1.f;
    sval[tid] = valid;
    float c = valid;
    #pragma unroll
    for (int off = 32; off > 0; off >>= 1) c += __shfl_down(c, off, 64);
    if ((tid & 63) == 0) scount[tid >> 6] = c;
    __syncthreads();
    const float denom = fmaxf(scount[0] + scount[1] + scount[2] + scount[3], 1.f);

    const float* base = seq_tokens + (size_t)sb * L_ * D_;
    const int cidx = tid & 127;
    const int rg = tid >> 7;
    f32x4 acc = {0.f, 0.f, 0.f, 0.f};
    for (int l = rg; l < L_; l += 2) {
        float vl = sval[l];
        f32x4 v = *reinterpret_cast<const f32x4*>(base + (size_t)l * D_ + cidx * 4);
        acc += v * vl;
    }
    spart[tid] = acc;
    __syncthreads();
    if (tid < 128) {
        f32x4 r = spart[tid] + spart[tid + 128];
        r *= (1.f / denom);
        *reinterpret_cast<f32x4*>(pooled + (size_t)sb * D_ + cidx * 4) = r;
    }
}

// ---------------- kernel 2: stat proj + LN, concat, group LN -> gi (bf16) ---------
__global__ __launch_bounds__(256) void gi_kernel(
    const float* __restrict__ ns_tokens,    // (B, 2048)
    const float* __restrict__ seq_stats,    // (S,B,6)
    const float* __restrict__ stat_W,       // (S,6,D)
    const float* __restrict__ stat_b,       // (S,D)
    const float* __restrict__ stat_ln_g,
    const float* __restrict__ stat_ln_b,
    const float* __restrict__ gin_gamma,    // (G)
    const float* __restrict__ gin_beta,
    const float* __restrict__ pooled,       // (S,B,D)
    __hip_bfloat16* __restrict__ gi)        // (S,B,G)
{
    const int sb = blockIdx.x;
    const int s = sb >> 8;
    const int b = sb & 255;
    const int tid = threadIdx.x;
    __shared__ float red[8];
    __shared__ float sstat[D_];

    float st[6];
    #pragma unroll
    for (int f = 0; f < 6; ++f) st[f] = seq_stats[(size_t)sb * 6 + f];

    float sp[2];
    #pragma unroll
    for (int k = 0; k < 2; ++k) {
        int d = tid + k * 256;
        float a = stat_b[s * D_ + d];
        #pragma unroll
        for (int f = 0; f < 6; ++f) a += st[f] * stat_W[(s * 6 + f) * D_ + d];
        sp[k] = a;
    }
    float ssum = block_sum256(sp[0] + sp[1], red);
    float ssq  = block_sum256(sp[0] * sp[0] + sp[1] * sp[1], red);
    float mu = ssum / D_;
    float var = ssq / D_ - mu * mu;
    float rinv = rsqrtf(var + 1e-5f);
    #pragma unroll
    for (int k = 0; k < 2; ++k) {
        int d = tid + k * 256;
        sstat[d] = (sp[k] - mu) * rinv * stat_ln_g[s * D_ + d] + stat_ln_b[s * D_ + d];
    }
    __syncthreads();

    float gv[12];
    float gsum = 0.f, gsq = 0.f;
    #pragma unroll
    for (int k = 0; k < 12; ++k) {
        int g = tid + k * 256;
        float v;
        if (g < 2048)       v = ns_tokens[(size_t)b * 2048 + g];
        else if (g < 2560)  v = pooled[(size_t)sb * D_ + (g - 2048)];
        else                v = sstat[g - 2560];
        gv[k] = v;
        gsum += v;
        gsq += v * v;
    }
    gsum = block_sum256(gsum, red);
    gsq  = block_sum256(gsq, red);
    mu = gsum / G_;
    var = gsq / G_ - mu * mu;
    rinv = rsqrtf(var + 1e-5f);
    #pragma unroll
    for (int k = 0; k < 12; ++k) {
        int g = tid + k * 256;
        float o = (gv[k] - mu) * rinv * gin_gamma[g] + gin_beta[g];
        gi[(size_t)sb * G_ + g] = __float2bfloat16(o);
    }
}

// ---------------- kernel 3: GEMM1 v8 -- gemm2-parity occupancy + depth-2 W pipeline ---------
// BM=256 (W1 read once), BN=32, BK=32, grid 1024 -> 4 blocks/CU (LDS 36 KB, VGPR<=128).
// Depth-2 W: iter kt loads W(kt+2) (4 scalar nt loads) + gll A(kt+1) (4 ops); vmcnt(8)
// guarantees W(kt+1) AND A(kt) resident (issued a full iter ago) -> zero-stall pack.
// wA/wB = 4 floats each (8 VGPR) -- r9's depth-2 idea without its spill.
#define G1_BODY(KT, CUR, NXT, WP, WQ)                                                   \
  {                                                                                     \
    const int kn2 = ((KT) + 2 < 96) ? (KT) + 2 : 95;                                    \
    const float* wp_ = Wb + (size_t)(kn2 * 32 + wkq * 4) * H_ + wn;                     \
    _Pragma("unroll")                                                                   \
    for (int j = 0; j < 4; ++j) WQ[j] = ntload1(wp_ + (size_t)j * H_);                  \
    {                                                                                   \
        const int kn1 = ((KT) + 1 < 96) ? (KT) + 1 : 95;                                \
        char* dst = reinterpret_cast<char*>(&As[NXT][0]);                               \
        const unsigned kbyte = (unsigned)kn1 * 64;                                      \
        _Pragma("unroll")                                                               \
        for (int j = 0; j < 4; ++j)                                                     \
            gll16(Ag + (aoff[j] + kbyte), dst + (wid * 64 + j * 16) * 64);              \
    }                                                                                   \
    asm volatile("s_waitcnt vmcnt(8)" ::: "memory");                                    \
    __builtin_amdgcn_sched_barrier(0);                                                  \
    {                                                                                   \
        const char* Al = reinterpret_cast<const char*>(&As[CUR][0]);                    \
        const char* Wl = reinterpret_cast<const char*>(&Ws[CUR][0]);                    \
        s16x8 b0 = *reinterpret_cast<const s16x8*>(Wl + offB[0]);                       \
        s16x8 b1r = *reinterpret_cast<const s16x8*>(Wl + offB[1]);                      \
        _Pragma("unroll")                                                               \
        for (int mf = 0; mf < 4; ++mf) {                                                \
            s16x8 af = *reinterpret_cast<const s16x8*>(Al + offA[mf]);                  \
            acc[mf][0] = __builtin_amdgcn_mfma_f32_16x16x32_bf16(af, b0, acc[mf][0], 0, 0, 0);  \
            acc[mf][1] = __builtin_amdgcn_mfma_f32_16x16x32_bf16(af, b1r, acc[mf][1], 0, 0, 0); \
        }                                                                               \
    }                                                                                   \
    {                                                                                   \
        unsigned long long pk =                                                         \
            (unsigned long long)f2bf(WP[0]) |                                           \
            ((unsigned long long)f2bf(WP[1]) << 16) |                                   \
            ((unsigned long long)f2bf(WP[2]) << 32) |                                   \
            ((unsigned long long)f2bf(WP[3]) << 48);                                    \
        *reinterpret_cast<unsigned long long*>(                                         \
            reinterpret_cast<char*>(&Ws[NXT][0]) + offW) = pk;                          \
    }                                                                                   \
    asm volatile("s_waitcnt lgkmcnt(0)" ::: "memory");                                  \
    __builtin_amdgcn_s_barrier();                                                       \
  }

__global__ __launch_bounds__(256, 4) void gemm1_kernel(
    const __hip_bfloat16* __restrict__ gi,
    const float* __restrict__ W1,
    const float* __restrict__ b1,
    __hip_bfloat16* __restrict__ hbuf)      // (S*Nq, B, H)
{
    // bijective XCD swizzle: 1024 blocks, 128/XCD -> each XCD owns sq {2x,2x+1} -> gi L2-local
    const int bid = blockIdx.x;
    const int wg = (bid & 7) * 128 + (bid >> 3);
    const int ntile = wg & 63;      // 0..63 (32-col tiles)
    const int sq = wg >> 6;         // 0..15
    const int s = sq >> 2;
    const int tid = threadIdx.x;
    const int lane = tid & 63;
    const int wid = tid >> 6;       // 0..3 (wave m-block: rows wid*64..+63)
    const int l15 = lane & 15;
    const int l4 = lane >> 4;       // k-chunk group 0..3

    __shared__ __align__(16) unsigned short As[2][256 * 32];   // 2 x 16 KB
    __shared__ __align__(16) unsigned short Ws[2][32 * 32];    // 2 x 2 KB

    const char* Ag = reinterpret_cast<const char*>(gi + (size_t)s * B_ * G_);
    const float* Wb = W1 + (size_t)sq * G_ * H_ + ntile * 32;

    f32x4 acc[4][2];
    #pragma unroll
    for (int i = 0; i < 4; ++i)
        #pragma unroll
        for (int j = 0; j < 2; ++j) acc[i][j] = (f32x4){0.f, 0.f, 0.f, 0.f};

    // A gll: 4 instrs/wave, each 16 rows x 64B; dest row = wid*64 + j*16 + (lane>>2),
    // dest chunk = lane&3 (linear: dest off = lane*16). Source chunk = (lane&3) ^ (row&3).
    unsigned aoff[4];
    #pragma unroll
    for (int j = 0; j < 4; ++j) {
        int row = wid * 64 + j * 16 + (lane >> 2);
        int c = (lane & 3) ^ (row & 3);
        aoff[j] = (unsigned)row * (G_ * 2) + c * 16;
    }

    // W stage: 32k x 32n f32; thread: n = tid&31, kq = tid>>5 (4 k each, k = kq*4..+3)
    const int wn = tid & 31;
    const int wkq = tid >> 5;
    // Ws[n][k] 64-B rows, 16-B chunks XOR'd by (n&3); thread's chunk c = wkq>>1, half = wkq&1
    const unsigned offW = (unsigned)(wn * 64 + (((wkq >> 1) ^ (wn & 3)) * 16) + (wkq & 1) * 8);

    // LDS read offsets (kt-invariant)
    unsigned offA[4], offB[2];
    #pragma unroll
    for (int mf = 0; mf < 4; ++mf) {
        int r = wid * 64 + mf * 16 + l15;
        offA[mf] = (unsigned)(r * 64 + ((l4 ^ (r & 3)) * 16));
    }
    #pragma unroll
    for (int nf = 0; nf < 2; ++nf) {
        int n = nf * 16 + l15;
        offB[nf] = (unsigned)(n * 64 + ((l4 ^ (n & 3)) * 16));
    }

    float wA[4], wB[4];

    // ---- prologue: gll A(0); W(0)->wA; W(1)->wB (kept in flight); pack wA -> Ws[0]
    {
        char* dst = reinterpret_cast<char*>(&As[0][0]);
        #pragma unroll
        for (int j = 0; j < 4; ++j)
            gll16(Ag + aoff[j], dst + (wid * 64 + j * 16) * 64);
        const float* wp0 = Wb + (size_t)(wkq * 4) * H_ + wn;
        #pragma unroll
        for (int j = 0; j < 4; ++j) wA[j] = ntload1(wp0 + (size_t)j * H_);
        const float* wp1 = Wb + (size_t)(32 + wkq * 4) * H_ + wn;
        #pragma unroll
        for (int j = 0; j < 4; ++j) wB[j] = ntload1(wp1 + (size_t)j * H_);
        asm volatile("s_waitcnt vmcnt(4)" ::: "memory");   // gll(4) + W0(4) retired; W1 in flight
        __builtin_amdgcn_sched_barrier(0);
        unsigned long long pk =
            (unsigned long long)f2bf(wA[0]) |
            ((unsigned long long)f2bf(wA[1]) << 16) |
            ((unsigned long long)f2bf(wA[2]) << 32) |
            ((unsigned long long)f2bf(wA[3]) << 48);
        *reinterpret_cast<unsigned long long*>(reinterpret_cast<char*>(&Ws[0][0]) + offW) = pk;
        asm volatile("s_waitcnt lgkmcnt(0)" ::: "memory");
        __builtin_amdgcn_s_barrier();
    }

    // ---- main loop: 96 K-steps, manual 2x unroll for static wA/wB ping-pong
    for (int kt = 0; kt < 96; kt += 2) {
        G1_BODY(kt,     0, 1, wB, wA);   // packs W(kt+1) from wB, loads W(kt+2)->wA
        G1_BODY(kt + 1, 1, 0, wA, wB);   // packs W(kt+2) from wA, loads W(kt+3)->wB
    }

    // ---- epilogue: + b1, silu, bf16 store
    const float* b1p = b1 + (size_t)sq * H_ + ntile * 32;
    __hip_bfloat16* hp = hbuf + (size_t)sq * B_ * H_;
    #pragma unroll
    for (int mf = 0; mf < 4; ++mf)
        #pragma unroll
        for (int nf = 0; nf < 2; ++nf)
            #pragma unroll
            for (int r = 0; r < 4; ++r) {
                int row = wid * 64 + mf * 16 + l4 * 4 + r;
                int col = nf * 16 + l15;
                float x = acc[mf][nf][r] + b1p[col];
                float sg = 1.f / (1.f + __expf(-x));
                hp[(size_t)row * H_ + ntile * 32 + col] = __float2bfloat16(x * sg);
            }
}

// ---------------- kernel 4: GEMM2 -- counted-vmcnt + nontemporal W2 loads (r14 exact) --------
__global__ __launch_bounds__(256, 4) void gemm2_kernel(
    const __hip_bfloat16* __restrict__ hbuf,
    const float* __restrict__ W2,
    __hip_bfloat16* __restrict__ qpre)      // (S*Nq, B, D)
{
    const int bid = blockIdx.x;
    const int wg = (bid & 7) * 64 + (bid >> 3);
    const int ntile = wg & 15;          // 0..15 (32-col tile)
    const int mtile = (wg >> 4) & 1;    // 0..1  (128-row tile)
    const int sq = wg >> 5;             // 0..15
    const int tid = threadIdx.x;
    const int lane = tid & 63;
    const int wid = tid >> 6;           // wave owns rows wid*32..+31

    __shared__ __align__(16) unsigned short As[2][128 * 64];   // 2 x 16 KB
    __shared__ __align__(16) unsigned short Ws[2][32 * 64];    // 2 x 4 KB

    const char* Ag = reinterpret_cast<const char*>(hbuf + ((size_t)sq * B_ + mtile * 128) * H_);
    const float* Wb = W2 + (size_t)sq * H_ * D_ + ntile * 32;

    f32x4 acc[2][2];
    #pragma unroll
    for (int i = 0; i < 2; ++i)
        #pragma unroll
        for (int j = 0; j < 2; ++j) acc[i][j] = (f32x4){0.f, 0.f, 0.f, 0.f};

    unsigned aoff[4];
    #pragma unroll
    for (int i = 0; i < 4; ++i) {
        int row = wid * 32 + i * 8 + (lane >> 3);
        int swz = ((lane >> 3) ^ (row >> 3)) & 7;
        aoff[i] = (unsigned)row * (H_ * 2) + (((lane & 7) ^ swz) * 16);
    }

    const int wn0 = (tid & 7) * 4;
    const int wk0 = (tid >> 3) * 2;
    unsigned offW[4];
    #pragma unroll
    for (int nn = 0; nn < 4; ++nn) {
        int row = wn0 + nn;
        int swz = (row ^ (row >> 3)) & 7;
        offW[nn] = (unsigned)((row * 128 + wk0 * 2) ^ (swz << 4));
    }

    unsigned offA[2][2], offB[2][2];
    #pragma unroll
    for (int kb = 0; kb < 2; ++kb) {
        #pragma unroll
        for (int mi = 0; mi < 2; ++mi) {
            int r = wid * 32 + mi * 16 + (lane & 15);
            int swz = (r ^ (r >> 3)) & 7;
            offA[kb][mi] = r * 128 + ((((lane >> 4) + kb * 4) ^ swz) * 16);
        }
        #pragma unroll
        for (int ni = 0; ni < 2; ++ni) {
            int r = ni * 16 + (lane & 15);
            int swz = (r ^ (r >> 3)) & 7;
            offB[kb][ni] = r * 128 + ((((lane >> 4) + kb * 4) ^ swz) * 16);
        }
    }

    // ---- prologue: gll A(0); load+pack W(0) -> Ws[0]
    {
        char* dst = reinterpret_cast<char*>(&As[0][0]);
        #pragma unroll
        for (int i = 0; i < 4; ++i)
            gll16(Ag + aoff[i], dst + (wid * 32 + i * 8) * 128);
        f32x4 w0[2];
        #pragma unroll
        for (int kk = 0; kk < 2; ++kk)
            w0[kk] = ntload4(Wb + (size_t)(wk0 + kk) * D_ + wn0);
        #pragma unroll
        for (int nn = 0; nn < 4; ++nn) {
            unsigned pk = (unsigned)f2bf(w0[0][nn]) | ((unsigned)f2bf(w0[1][nn]) << 16);
            *reinterpret_cast<unsigned*>(reinterpret_cast<char*>(&Ws[0][0]) + offW[nn]) = pk;
        }
        asm volatile("s_waitcnt lgkmcnt(0)" ::: "memory");
        __builtin_amdgcn_s_barrier();
    }

    // ---- main loop: 32 K-steps, one barrier each, vmcnt never drained
    for (int kt = 0; kt < H_ / 64; ++kt) {
        const int cur = kt & 1, nxt = cur ^ 1;
        const int kn = (kt < H_ / 64 - 1) ? kt + 1 : H_ / 64 - 1;

        f32x4 wreg[2];
        {
            const float* wp = Wb + (size_t)(kn * 64 + wk0) * D_ + wn0;
            #pragma unroll
            for (int kk = 0; kk < 2; ++kk)
                wreg[kk] = ntload4(wp + (size_t)kk * D_);
        }
        {
            char* dst = reinterpret_cast<char*>(&As[nxt][0]);
            const unsigned kbyte = (unsigned)kn * 128;
            #pragma unroll
            for (int i = 0; i < 4; ++i)
                gll16(Ag + (aoff[i] + kbyte), dst + (wid * 32 + i * 8) * 128);
        }
        asm volatile("s_waitcnt vmcnt(6)" ::: "memory");
        __builtin_amdgcn_sched_barrier(0);

        const char* Al = reinterpret_cast<const char*>(&As[cur][0]);
        const char* Wl = reinterpret_cast<const char*>(&Ws[cur][0]);
        #pragma unroll
        for (int kb = 0; kb < 2; ++kb) {
            s16x8 af[2], bfr[2];
            #pragma unroll
            for (int mi = 0; mi < 2; ++mi)
                af[mi] = *reinterpret_cast<const s16x8*>(Al + offA[kb][mi]);
            #pragma unroll
            for (int ni = 0; ni < 2; ++ni)
                bfr[ni] = *reinterpret_cast<const s16x8*>(Wl + offB[kb][ni]);
            #pragma unroll
            for (int mi = 0; mi < 2; ++mi)
                #pragma unroll
                for (int ni = 0; ni < 2; ++ni)
                    acc[mi][ni] = __builtin_amdgcn_mfma_f32_16x16x32_bf16(af[mi], bfr[ni], acc[mi][ni], 0, 0, 0);
        }

        #pragma unroll
        for (int nn = 0; nn < 4; ++nn) {
            unsigned pk = (unsigned)f2bf(wreg[0][nn]) | ((unsigned)f2bf(wreg[1][nn]) << 16);
            *reinterpret_cast<unsigned*>(reinterpret_cast<char*>(&Ws[nxt][0]) + offW[nn]) = pk;
        }
        asm volatile("s_waitcnt lgkmcnt(0)" ::: "memory");
        __builtin_amdgcn_s_barrier();
    }

    // ---- epilogue: bf16 store
    #pragma unroll
    for (int mi = 0; mi < 2; ++mi)
        #pragma unroll
        for (int ni = 0; ni < 2; ++ni)
            #pragma unroll
            for (int r = 0; r < 4; ++r) {
                int row = mtile * 128 + wid * 32 + mi * 16 + ((lane >> 4) << 2) + r;
                int col = ntile * 32 + ni * 16 + (lane & 15);
                qpre[((size_t)sq * B_ + row) * D_ + col] = __float2bfloat16(acc[mi][ni][r]);
            }
}

// ---------------- kernel 5: +b2, LayerNorm over D, transposed write ----------------
__global__ __launch_bounds__(256) void lnout_kernel(
    const __hip_bfloat16* __restrict__ qpre,   // (S*Nq, B, D) bf16
    const float* __restrict__ b2,
    const float* __restrict__ lng,
    const float* __restrict__ lnb,
    float* __restrict__ out)          // (S,B,Nq,D)
{
    const int idx = blockIdx.x;       // sq*B + b
    const int sq = idx >> 8;
    const int b = idx & 255;
    const int tid = threadIdx.x;
    __shared__ float red[8];

    float v[2];
    #pragma unroll
    for (int k = 0; k < 2; ++k) {
        int d = tid + k * 256;
        v[k] = __bfloat162float(qpre[(size_t)idx * D_ + d]) + b2[sq * D_ + d];
    }
    float sum = block_sum256(v[0] + v[1], red);
    float sq2 = block_sum256(v[0] * v[0] + v[1] * v[1], red);
    float mu = sum / D_;
    float var = sq2 / D_ - mu * mu;
    float rinv = rsqrtf(var + 1e-5f);
    const int s = sq >> 2, q = sq & 3;
    #pragma unroll
    for (int k = 0; k < 2; ++k) {
        int d = tid + k * 256;
        float o = (v[k] - mu) * rinv * lng[sq * D_ + d] + lnb[sq * D_ + d];
        out[(((size_t)s * B_ + b) * NQ_ + q) * D_ + d] = o;
    }
}

extern "C" void kernel_launch(void* const* d_in, const int* in_sizes, int n_in,
                              void* d_out, int out_size, void* d_ws, size_t ws_size,
                              hipStream_t stream) {
    const float* ns_tokens   = (const float*)d_in[0];
    const float* seq_tokens  = (const float*)d_in[1];
    const unsigned char* masks = (const unsigned char*)d_in[2];
    const float* seq_stats   = (const float*)d_in[3];
    const float* gin_gamma   = (const float*)d_in[4];
    const float* gin_beta    = (const float*)d_in[5];
    const float* stat_W      = (const float*)d_in[6];
    const float* stat_b      = (const float*)d_in[7];
    const float* stat_ln_g   = (const float*)d_in[8];
    const float* stat_ln_b   = (const float*)d_in[9];
    const float* W1          = (const float*)d_in[10];
    const float* b1          = (const float*)d_in[11];
    const float* W2          = (const float*)d_in[12];
    const float* b2          = (const float*)d_in[13];
    const float* ln_g        = (const float*)d_in[14];
    const float* ln_b        = (const float*)d_in[15];
    float* out = (float*)d_out;

    // ws layout: pooled f32 2 MB | gi bf16 6 MB | h bf16 16.8 MB | qpre bf16 4.2 MB
    char* ws = (char*)d_ws;
    float* pooled        = (float*)(ws);
    __hip_bfloat16* gi   = (__hip_bfloat16*)(ws + 2097152);
    __hip_bfloat16* hbuf = (__hip_bfloat16*)(ws + 2097152 + 6291456);
    __hip_bfloat16* qpre = (__hip_bfloat16*)(ws + 2097152 + 6291456 + 16777216);

    pool_kernel<<<dim3(S_ * B_), dim3(256), 0, stream>>>(seq_tokens, masks, pooled);
    gi_kernel<<<dim3(S_ * B_), dim3(256), 0, stream>>>(ns_tokens, seq_stats, stat_W, stat_b,
                                                       stat_ln_g, stat_ln_b, gin_gamma, gin_beta,
                                                       pooled, gi);
    gemm1_kernel<<<dim3(1024), dim3(256), 0, stream>>>(gi, W1, b1, hbuf);
    gemm2_kernel<<<dim3(512), dim3(256), 0, stream>>>(hbuf, W2, qpre);
    lnout_kernel<<<dim3(S_ * NQ_ * B_), dim3(256), 0, stream>>>(qpre, b2, ln_g, ln_b, out);
}

// Round 16
// 261.894 us; speedup vs baseline: 1.3450x; 1.3450x over previous
//
#include <hip/hip_runtime.h>
#include <hip/hip_bf16.h>

#define S_ 4
#define B_ 256
#define L_ 256
#define D_ 512
#define NQ_ 4
#define H_ 2048
#define G_ 3072

typedef __attribute__((ext_vector_type(4))) float f32x4;
typedef __attribute__((ext_vector_type(8))) short s16x8;

__device__ __forceinline__ unsigned short f2bf(float x) {
    __hip_bfloat16 hb = __float2bfloat16(x);
    return reinterpret_cast<unsigned short&>(hb);
}

// nontemporal f32x4 load: W streams have zero reuse -> don't let them evict L2-resident A
__device__ __forceinline__ f32x4 ntload4(const float* p) {
    return __builtin_nontemporal_load(reinterpret_cast<const f32x4*>(p));
}

// async global->LDS, 16B per lane, LDS dest = wave-uniform base + lane*16
__device__ __forceinline__ void gll16(const void* g, void* l) {
    __builtin_amdgcn_global_load_lds(
        (const __attribute__((address_space(1))) unsigned int*)g,
        (__attribute__((address_space(3))) unsigned int*)l, 16, 0, 0);
}

// block-wide sum for 256-thread blocks; red is __shared__ float[8]
__device__ __forceinline__ float block_sum256(float v, float* red) {
    #pragma unroll
    for (int off = 32; off > 0; off >>= 1) v += __shfl_down(v, off, 64);
    int tid = threadIdx.x;
    int lane = tid & 63, wid = tid >> 6;
    if (lane == 0) red[wid] = v;
    __syncthreads();
    float r = (tid < 4) ? red[tid] : 0.f;
    #pragma unroll
    for (int off = 4; off > 0; off >>= 1) r += __shfl_down(r, off, 64);
    if (tid == 0) red[0] = r;
    __syncthreads();
    float out = red[0];
    __syncthreads();
    return out;
}

// ---------------- kernel 1: masked mean pool over L ----------------
__global__ __launch_bounds__(256) void pool_kernel(
    const float* __restrict__ seq_tokens,
    const unsigned char* __restrict__ masks_raw,
    float* __restrict__ pooled)                // (S,B,D)
{
    const int sb = blockIdx.x;
    const int tid = threadIdx.x;
    __shared__ float sval[L_];
    __shared__ float scount[4];
    __shared__ f32x4 spart[256];
    __shared__ int is_bool_flag;

    if (tid == 0) is_bool_flag = 0;
    __syncthreads();
    {
        unsigned int w = reinterpret_cast<const unsigned int*>(masks_raw)[tid];
        if (w & 0xFFFFFF00u) is_bool_flag = 1;   // benign race, same value
    }
    __syncthreads();
    const bool is_bool = (is_bool_flag != 0);

    int mval;
    if (is_bool) mval = masks_raw[(size_t)sb * L_ + tid];
    else         mval = reinterpret_cast<const int*>(masks_raw)[(size_t)sb * L_ + tid];
    float valid = mval ? 0.f : 1.f;
    sval[tid] = valid;
    float c = valid;
    #pragma unroll
    for (int off = 32; off > 0; off >>= 1) c += __shfl_down(c, off, 64);
    if ((tid & 63) == 0) scount[tid >> 6] = c;
    __syncthreads();
    const float denom = fmaxf(scount[0] + scount[1] + scount[2] + scount[3], 1.f);

    const float* base = seq_tokens + (size_t)sb * L_ * D_;
    const int cidx = tid & 127;
    const int rg = tid >> 7;
    f32x4 acc = {0.f, 0.f, 0.f, 0.f};
    for (int l = rg; l < L_; l += 2) {
        float vl = sval[l];
        f32x4 v = *reinterpret_cast<const f32x4*>(base + (size_t)l * D_ + cidx * 4);
        acc += v * vl;
    }
    spart[tid] = acc;
    __syncthreads();
    if (tid < 128) {
        f32x4 r = spart[tid] + spart[tid + 128];
        r *= (1.f / denom);
        *reinterpret_cast<f32x4*>(pooled + (size_t)sb * D_ + cidx * 4) = r;
    }
}

// ---------------- kernel 2: stat proj + LN, concat, group LN -> gi (bf16) ---------
__global__ __launch_bounds__(256) void gi_kernel(
    const float* __restrict__ ns_tokens,    // (B, 2048)
    const float* __restrict__ seq_stats,    // (S,B,6)
    const float* __restrict__ stat_W,       // (S,6,D)
    const float* __restrict__ stat_b,       // (S,D)
    const float* __restrict__ stat_ln_g,
    const float* __restrict__ stat_ln_b,
    const float* __restrict__ gin_gamma,    // (G)
    const float* __restrict__ gin_beta,
    const float* __restrict__ pooled,       // (S,B,D)
    __hip_bfloat16* __restrict__ gi)        // (S,B,G)
{
    const int sb = blockIdx.x;
    const int s = sb >> 8;
    const int b = sb & 255;
    const int tid = threadIdx.x;
    __shared__ float red[8];
    __shared__ float sstat[D_];

    float st[6];
    #pragma unroll
    for (int f = 0; f < 6; ++f) st[f] = seq_stats[(size_t)sb * 6 + f];

    float sp[2];
    #pragma unroll
    for (int k = 0; k < 2; ++k) {
        int d = tid + k * 256;
        float a = stat_b[s * D_ + d];
        #pragma unroll
        for (int f = 0; f < 6; ++f) a += st[f] * stat_W[(s * 6 + f) * D_ + d];
        sp[k] = a;
    }
    float ssum = block_sum256(sp[0] + sp[1], red);
    float ssq  = block_sum256(sp[0] * sp[0] + sp[1] * sp[1], red);
    float mu = ssum / D_;
    float var = ssq / D_ - mu * mu;
    float rinv = rsqrtf(var + 1e-5f);
    #pragma unroll
    for (int k = 0; k < 2; ++k) {
        int d = tid + k * 256;
        sstat[d] = (sp[k] - mu) * rinv * stat_ln_g[s * D_ + d] + stat_ln_b[s * D_ + d];
    }
    __syncthreads();

    float gv[12];
    float gsum = 0.f, gsq = 0.f;
    #pragma unroll
    for (int k = 0; k < 12; ++k) {
        int g = tid + k * 256;
        float v;
        if (g < 2048)       v = ns_tokens[(size_t)b * 2048 + g];
        else if (g < 2560)  v = pooled[(size_t)sb * D_ + (g - 2048)];
        else                v = sstat[g - 2560];
        gv[k] = v;
        gsum += v;
        gsq += v * v;
    }
    gsum = block_sum256(gsum, red);
    gsq  = block_sum256(gsq, red);
    mu = gsum / G_;
    var = gsq / G_ - mu * mu;
    rinv = rsqrtf(var + 1e-5f);
    #pragma unroll
    for (int k = 0; k < 12; ++k) {
        int g = tid + k * 256;
        float o = (gv[k] - mu) * rinv * gin_gamma[g] + gin_beta[g];
        gi[(size_t)sb * G_ + g] = __float2bfloat16(o);
    }
}

// ---------------- kernel 3: GEMM1 -- counted-vmcnt pipeline + nontemporal W loads ----------
__global__ __launch_bounds__(256) void gemm1_kernel(
    const __hip_bfloat16* __restrict__ gi,
    const float* __restrict__ W1,
    const float* __restrict__ b1,
    __hip_bfloat16* __restrict__ hbuf)      // (S*Nq, B, H)
{
    const int bid = blockIdx.x;
    const int wg = (bid & 7) * 64 + (bid >> 3);
    const int ntile = wg & 31;      // 0..31
    const int sq = wg >> 5;         // 0..15
    const int s = sq >> 2;
    const int tid = threadIdx.x;
    const int lane = tid & 63;
    const int wid = tid >> 6;       // 0..3 (wave m-block)

    __shared__ __align__(16) unsigned short As[2][256 * 64];
    __shared__ __align__(16) unsigned short Ws[2][64 * 64];

    const char* Ag = reinterpret_cast<const char*>(gi + (size_t)s * B_ * G_);
    const float* Wb = W1 + (size_t)sq * G_ * H_ + ntile * 64;

    f32x4 acc[4][4];
    #pragma unroll
    for (int i = 0; i < 4; ++i)
        #pragma unroll
        for (int j = 0; j < 4; ++j) acc[i][j] = (f32x4){0.f, 0.f, 0.f, 0.f};

    unsigned aoff[8];
    #pragma unroll
    for (int i = 0; i < 8; ++i) {
        int row = wid * 64 + i * 8 + (lane >> 3);
        int swz = ((lane >> 3) ^ i) & 7;
        aoff[i] = (unsigned)row * (G_ * 2) + (((lane & 7) ^ swz) * 16);
    }

    const int wn0 = (tid & 15) * 4;
    const int wk0 = (tid >> 4) * 4;
    unsigned offW[4];
    #pragma unroll
    for (int nn = 0; nn < 4; ++nn) {
        int row = wn0 + nn;
        int swz = (row ^ (row >> 3)) & 7;
        offW[nn] = (unsigned)((row * 128 + wk0 * 2) ^ (swz << 4));
    }

    unsigned offA[2][4], offB[2][4];
    #pragma unroll
    for (int kb = 0; kb < 2; ++kb) {
        #pragma unroll
        for (int mi = 0; mi < 4; ++mi) {
            int r = wid * 64 + mi * 16 + (lane & 15);
            int swz = (r ^ (r >> 3)) & 7;
            offA[kb][mi] = r * 128 + ((((lane >> 4) + kb * 4) ^ swz) * 16);
        }
        #pragma unroll
        for (int ni = 0; ni < 4; ++ni) {
            int r = ni * 16 + (lane & 15);
            int swz = (r ^ (r >> 3)) & 7;
            offB[kb][ni] = r * 128 + ((((lane >> 4) + kb * 4) ^ swz) * 16);
        }
    }

    // ---- prologue
    {
        char* dst = reinterpret_cast<char*>(&As[0][0]);
        #pragma unroll
        for (int i = 0; i < 8; ++i)
            gll16(Ag + aoff[i], dst + (wid * 64 + i * 8) * 128);
        f32x4 w0[4];
        #pragma unroll
        for (int kk = 0; kk < 4; ++kk)
            w0[kk] = ntload4(Wb + (size_t)(wk0 + kk) * H_ + wn0);
        #pragma unroll
        for (int nn = 0; nn < 4; ++nn) {
            unsigned long long pk =
                (unsigned long long)f2bf(w0[0][nn]) |
                ((unsigned long long)f2bf(w0[1][nn]) << 16) |
                ((unsigned long long)f2bf(w0[2][nn]) << 32) |
                ((unsigned long long)f2bf(w0[3][nn]) << 48);
            *reinterpret_cast<unsigned long long*>(reinterpret_cast<char*>(&Ws[0][0]) + offW[nn]) = pk;
        }
        asm volatile("s_waitcnt lgkmcnt(0)" ::: "memory");
        __builtin_amdgcn_s_barrier();
    }

    // ---- main loop: 48 K-steps, one barrier each, vmcnt never drained
    for (int kt = 0; kt < G_ / 64; ++kt) {
        const int cur = kt & 1, nxt = cur ^ 1;
        const int kn = (kt < G_ / 64 - 1) ? kt + 1 : G_ / 64 - 1;

        f32x4 wreg[4];
        {
            const float* wp = Wb + (size_t)(kn * 64 + wk0) * H_ + wn0;
            #pragma unroll
            for (int kk = 0; kk < 4; ++kk)
                wreg[kk] = ntload4(wp + (size_t)kk * H_);
        }
        {
            char* dst = reinterpret_cast<char*>(&As[nxt][0]);
            const unsigned kbyte = (unsigned)kn * 128;
            #pragma unroll
            for (int i = 0; i < 8; ++i)
                gll16(Ag + (aoff[i] + kbyte), dst + (wid * 64 + i * 8) * 128);
        }
        asm volatile("s_waitcnt vmcnt(12)" ::: "memory");
        __builtin_amdgcn_sched_barrier(0);

        const char* Al = reinterpret_cast<const char*>(&As[cur][0]);
        const char* Wl = reinterpret_cast<const char*>(&Ws[cur][0]);
        #pragma unroll
        for (int kb = 0; kb < 2; ++kb) {
            s16x8 af[4], bfr[4];
            #pragma unroll
            for (int mi = 0; mi < 4; ++mi)
                af[mi] = *reinterpret_cast<const s16x8*>(Al + offA[kb][mi]);
            #pragma unroll
            for (int ni = 0; ni < 4; ++ni)
                bfr[ni] = *reinterpret_cast<const s16x8*>(Wl + offB[kb][ni]);
            #pragma unroll
            for (int mi = 0; mi < 4; ++mi)
                #pragma unroll
                for (int ni = 0; ni < 4; ++ni)
                    acc[mi][ni] = __builtin_amdgcn_mfma_f32_16x16x32_bf16(af[mi], bfr[ni], acc[mi][ni], 0, 0, 0);
        }

        #pragma unroll
        for (int nn = 0; nn < 4; ++nn) {
            unsigned long long pk =
                (unsigned long long)f2bf(wreg[0][nn]) |
                ((unsigned long long)f2bf(wreg[1][nn]) << 16) |
                ((unsigned long long)f2bf(wreg[2][nn]) << 32) |
                ((unsigned long long)f2bf(wreg[3][nn]) << 48);
            *reinterpret_cast<unsigned long long*>(reinterpret_cast<char*>(&Ws[nxt][0]) + offW[nn]) = pk;
        }
        asm volatile("s_waitcnt lgkmcnt(0)" ::: "memory");
        __builtin_amdgcn_s_barrier();
    }

    // ---- epilogue: + b1, silu, bf16 store
    const float* b1p = b1 + (size_t)sq * H_ + ntile * 64;
    __hip_bfloat16* hp = hbuf + (size_t)sq * B_ * H_;
    #pragma unroll
    for (int mi = 0; mi < 4; ++mi)
        #pragma unroll
        for (int ni = 0; ni < 4; ++ni)
            #pragma unroll
            for (int r = 0; r < 4; ++r) {
                int row = wid * 64 + mi * 16 + ((lane >> 4) << 2) + r;
                int coll = ni * 16 + (lane & 15);
                float x = acc[mi][ni][r] + b1p[coll];
                float sg = 1.f / (1.f + __expf(-x));
                hp[(size_t)row * H_ + ntile * 64 + coll] = __float2bfloat16(x * sg);
            }
}

// ---------------- kernel 4: GEMM2 -- counted-vmcnt + nontemporal W2 loads ----------------
__global__ __launch_bounds__(256, 4) void gemm2_kernel(
    const __hip_bfloat16* __restrict__ hbuf,
    const float* __restrict__ W2,
    __hip_bfloat16* __restrict__ qpre)      // (S*Nq, B, D)
{
    const int bid = blockIdx.x;
    const int wg = (bid & 7) * 64 + (bid >> 3);
    const int ntile = wg & 15;          // 0..15 (32-col tile)
    const int mtile = (wg >> 4) & 1;    // 0..1  (128-row tile)
    const int sq = wg >> 5;             // 0..15
    const int tid = threadIdx.x;
    const int lane = tid & 63;
    const int wid = tid >> 6;           // wave owns rows wid*32..+31

    __shared__ __align__(16) unsigned short As[2][128 * 64];   // 2 x 16 KB
    __shared__ __align__(16) unsigned short Ws[2][32 * 64];    // 2 x 4 KB

    const char* Ag = reinterpret_cast<const char*>(hbuf + ((size_t)sq * B_ + mtile * 128) * H_);
    const float* Wb = W2 + (size_t)sq * H_ * D_ + ntile * 32;

    f32x4 acc[2][2];
    #pragma unroll
    for (int i = 0; i < 2; ++i)
        #pragma unroll
        for (int j = 0; j < 2; ++j) acc[i][j] = (f32x4){0.f, 0.f, 0.f, 0.f};

    unsigned aoff[4];
    #pragma unroll
    for (int i = 0; i < 4; ++i) {
        int row = wid * 32 + i * 8 + (lane >> 3);
        int swz = ((lane >> 3) ^ (row >> 3)) & 7;
        aoff[i] = (unsigned)row * (H_ * 2) + (((lane & 7) ^ swz) * 16);
    }

    const int wn0 = (tid & 7) * 4;
    const int wk0 = (tid >> 3) * 2;
    unsigned offW[4];
    #pragma unroll
    for (int nn = 0; nn < 4; ++nn) {
        int row = wn0 + nn;
        int swz = (row ^ (row >> 3)) & 7;
        offW[nn] = (unsigned)((row * 128 + wk0 * 2) ^ (swz << 4));
    }

    unsigned offA[2][2], offB[2][2];
    #pragma unroll
    for (int kb = 0; kb < 2; ++kb) {
        #pragma unroll
        for (int mi = 0; mi < 2; ++mi) {
            int r = wid * 32 + mi * 16 + (lane & 15);
            int swz = (r ^ (r >> 3)) & 7;
            offA[kb][mi] = r * 128 + ((((lane >> 4) + kb * 4) ^ swz) * 16);
        }
        #pragma unroll
        for (int ni = 0; ni < 2; ++ni) {
            int r = ni * 16 + (lane & 15);
            int swz = (r ^ (r >> 3)) & 7;
            offB[kb][ni] = r * 128 + ((((lane >> 4) + kb * 4) ^ swz) * 16);
        }
    }

    // ---- prologue: gll A(0); load+pack W(0) -> Ws[0]
    {
        char* dst = reinterpret_cast<char*>(&As[0][0]);
        #pragma unroll
        for (int i = 0; i < 4; ++i)
            gll16(Ag + aoff[i], dst + (wid * 32 + i * 8) * 128);
        f32x4 w0[2];
        #pragma unroll
        for (int kk = 0; kk < 2; ++kk)
            w0[kk] = ntload4(Wb + (size_t)(wk0 + kk) * D_ + wn0);
        #pragma unroll
        for (int nn = 0; nn < 4; ++nn) {
            unsigned pk = (unsigned)f2bf(w0[0][nn]) | ((unsigned)f2bf(w0[1][nn]) << 16);
            *reinterpret_cast<unsigned*>(reinterpret_cast<char*>(&Ws[0][0]) + offW[nn]) = pk;
        }
        asm volatile("s_waitcnt lgkmcnt(0)" ::: "memory");
        __builtin_amdgcn_s_barrier();
    }

    // ---- main loop: 32 K-steps, one barrier each, vmcnt never drained
    for (int kt = 0; kt < H_ / 64; ++kt) {
        const int cur = kt & 1, nxt = cur ^ 1;
        const int kn = (kt < H_ / 64 - 1) ? kt + 1 : H_ / 64 - 1;

        f32x4 wreg[2];
        {
            const float* wp = Wb + (size_t)(kn * 64 + wk0) * D_ + wn0;
            #pragma unroll
            for (int kk = 0; kk < 2; ++kk)
                wreg[kk] = ntload4(wp + (size_t)kk * D_);
        }
        {
            char* dst = reinterpret_cast<char*>(&As[nxt][0]);
            const unsigned kbyte = (unsigned)kn * 128;
            #pragma unroll
            for (int i = 0; i < 4; ++i)
                gll16(Ag + (aoff[i] + kbyte), dst + (wid * 32 + i * 8) * 128);
        }
        asm volatile("s_waitcnt vmcnt(6)" ::: "memory");
        __builtin_amdgcn_sched_barrier(0);

        const char* Al = reinterpret_cast<const char*>(&As[cur][0]);
        const char* Wl = reinterpret_cast<const char*>(&Ws[cur][0]);
        #pragma unroll
        for (int kb = 0; kb < 2; ++kb) {
            s16x8 af[2], bfr[2];
            #pragma unroll
            for (int mi = 0; mi < 2; ++mi)
                af[mi] = *reinterpret_cast<const s16x8*>(Al + offA[kb][mi]);
            #pragma unroll
            for (int ni = 0; ni < 2; ++ni)
                bfr[ni] = *reinterpret_cast<const s16x8*>(Wl + offB[kb][ni]);
            #pragma unroll
            for (int mi = 0; mi < 2; ++mi)
                #pragma unroll
                for (int ni = 0; ni < 2; ++ni)
                    acc[mi][ni] = __builtin_amdgcn_mfma_f32_16x16x32_bf16(af[mi], bfr[ni], acc[mi][ni], 0, 0, 0);
        }

        #pragma unroll
        for (int nn = 0; nn < 4; ++nn) {
            unsigned pk = (unsigned)f2bf(wreg[0][nn]) | ((unsigned)f2bf(wreg[1][nn]) << 16);
            *reinterpret_cast<unsigned*>(reinterpret_cast<char*>(&Ws[nxt][0]) + offW[nn]) = pk;
        }
        asm volatile("s_waitcnt lgkmcnt(0)" ::: "memory");
        __builtin_amdgcn_s_barrier();
    }

    // ---- epilogue: bf16 store
    #pragma unroll
    for (int mi = 0; mi < 2; ++mi)
        #pragma unroll
        for (int ni = 0; ni < 2; ++ni)
            #pragma unroll
            for (int r = 0; r < 4; ++r) {
                int row = mtile * 128 + wid * 32 + mi * 16 + ((lane >> 4) << 2) + r;
                int col = ntile * 32 + ni * 16 + (lane & 15);
                qpre[((size_t)sq * B_ + row) * D_ + col] = __float2bfloat16(acc[mi][ni][r]);
            }
}

// ---------------- kernel 5: +b2, LayerNorm over D, transposed write ----------------
__global__ __launch_bounds__(256) void lnout_kernel(
    const __hip_bfloat16* __restrict__ qpre,   // (S*Nq, B, D) bf16
    const float* __restrict__ b2,
    const float* __restrict__ lng,
    const float* __restrict__ lnb,
    float* __restrict__ out)          // (S,B,Nq,D)
{
    const int idx = blockIdx.x;       // sq*B + b
    const int sq = idx >> 8;
    const int b = idx & 255;
    const int tid = threadIdx.x;
    __shared__ float red[8];

    float v[2];
    #pragma unroll
    for (int k = 0; k < 2; ++k) {
        int d = tid + k * 256;
        v[k] = __bfloat162float(qpre[(size_t)idx * D_ + d]) + b2[sq * D_ + d];
    }
    float sum = block_sum256(v[0] + v[1], red);
    float sq2 = block_sum256(v[0] * v[0] + v[1] * v[1], red);
    float mu = sum / D_;
    float var = sq2 / D_ - mu * mu;
    float rinv = rsqrtf(var + 1e-5f);
    const int s = sq >> 2, q = sq & 3;
    #pragma unroll
    for (int k = 0; k < 2; ++k) {
        int d = tid + k * 256;
        float o = (v[k] - mu) * rinv * lng[sq * D_ + d] + lnb[sq * D_ + d];
        out[(((size_t)s * B_ + b) * NQ_ + q) * D_ + d] = o;
    }
}

extern "C" void kernel_launch(void* const* d_in, const int* in_sizes, int n_in,
                              void* d_out, int out_size, void* d_ws, size_t ws_size,
                              hipStream_t stream) {
    const float* ns_tokens   = (const float*)d_in[0];
    const float* seq_tokens  = (const float*)d_in[1];
    const unsigned char* masks = (const unsigned char*)d_in[2];
    const float* seq_stats   = (const float*)d_in[3];
    const float* gin_gamma   = (const float*)d_in[4];
    const float* gin_beta    = (const float*)d_in[5];
    const float* stat_W      = (const float*)d_in[6];
    const float* stat_b      = (const float*)d_in[7];
    const float* stat_ln_g   = (const float*)d_in[8];
    const float* stat_ln_b   = (const float*)d_in[9];
    const float* W1          = (const float*)d_in[10];
    const float* b1          = (const float*)d_in[11];
    const float* W2          = (const float*)d_in[12];
    const float* b2          = (const float*)d_in[13];
    const float* ln_g        = (const float*)d_in[14];
    const float* ln_b        = (const float*)d_in[15];
    float* out = (float*)d_out;

    // ws layout: pooled f32 2 MB | gi bf16 6 MB | h bf16 16.8 MB | qpre bf16 4.2 MB
    char* ws = (char*)d_ws;
    float* pooled        = (float*)(ws);
    __hip_bfloat16* gi   = (__hip_bfloat16*)(ws + 2097152);
    __hip_bfloat16* hbuf = (__hip_bfloat16*)(ws + 2097152 + 6291456);
    __hip_bfloat16* qpre = (__hip_bfloat16*)(ws + 2097152 + 6291456 + 16777216);

    pool_kernel<<<dim3(S_ * B_), dim3(256), 0, stream>>>(seq_tokens, masks, pooled);
    gi_kernel<<<dim3(S_ * B_), dim3(256), 0, stream>>>(ns_tokens, seq_stats, stat_W, stat_b,
                                                       stat_ln_g, stat_ln_b, gin_gamma, gin_beta,
                                                       pooled, gi);
    gemm1_kernel<<<dim3(32 * S_ * NQ_), dim3(256), 0, stream>>>(gi, W1, b1, hbuf);
    gemm2_kernel<<<dim3(512), dim3(256), 0, stream>>>(hbuf, W2, qpre);
    lnout_kernel<<<dim3(S_ * NQ_ * B_), dim3(256), 0, stream>>>(qpre, b2, ln_g, ln_b, out);
}